// Round 3
// baseline (961.709 us; speedup 1.0000x reference)
//
#include <hip/hip_runtime.h>

// Sparse submanifold 3x3x3 conv (64->64) + BatchNorm(batch stats) + LeakyReLU(0.01)
// Rulebook strategy with OCCUPANCY BITMASK (1 bit/cell = 1.2MB, L2-resident):
//   K1 memset occ bitmask + counters/stats (NO 39MB grid memset: grid cells are
//      only read where occ bit is set, and those were written by scatter_k)
//   K2 scatter: grid[lin]=i, atomicOr occ bit
//   K3 rulebook: per-voxel thread probes 9 rows x 3 bits in the bitmask (L2 hits),
//      reads int grid only on actual hits (~60K), appends (i,j) to per-offset lists
//   K4 center GEMM: out = feat @ W[13] (plain store => also initializes out)
//   K5 per-offset gather-GEMM, atomicAdd scatter into out
//   K6 channel sum/sumsq reduction
//   K7 normalize + leaky relu (in place on out)

#define DD 96
#define HH 320
#define WW 320
#define GRID_ELEMS (DD * HH * WW)
#define OCC_WORDS (GRID_ELEMS / 32)   // 307,200 words = 1.2 MB; WW=320 divisible by 32 => rows word-aligned
#define CIN 64
#define COUT 64
#define PAIR_CAP 16384   // per-offset list capacity; E[count]~2300 => ample
#define EPSV 1e-5f
#define SLOPE 0.01f

__global__ void scatter_k(const int* __restrict__ coords, int* __restrict__ grid,
                          unsigned* __restrict__ occ, int N) {
    int i = blockIdx.x * 256 + threadIdx.x;
    if (i >= N) return;
    int z = coords[3 * i], y = coords[3 * i + 1], x = coords[3 * i + 2];
    int l = (z * HH + y) * WW + x;
    grid[l] = i;
    atomicOr(&occ[l >> 5], 1u << (l & 31));
}

// One thread per voxel. 18 independent bitmask word loads (L2-resident 1.2MB)
// cover the 3x3x3 neighborhood; int grid (39MB) read only on set bits (~0.4/voxel).
__global__ void rulebook_k(const int* __restrict__ coords, const int* __restrict__ grid,
                           const unsigned* __restrict__ occ,
                           int* __restrict__ cnt, int2* __restrict__ pairs, int N) {
    int i = blockIdx.x * 256 + threadIdx.x;
    if (i >= N) return;
    int z = coords[3 * i], y = coords[3 * i + 1], x = coords[3 * i + 2];
    int lo = x > 0 ? x - 1 : 0;
    int hi = x < WW - 1 ? x + 1 : WW - 1;
    int wlo = lo >> 5, whi = hi >> 5;

    unsigned wa[9], wb9[9];
    int rwb[9];
#pragma unroll
    for (int r = 0; r < 9; ++r) {
        int zz = z + r / 3 - 1;
        int yy = y + r % 3 - 1;
        bool ok = ((unsigned)zz < DD) && ((unsigned)yy < HH);
        int base = (zz * HH + yy) * WW;      // word-aligned (WW % 32 == 0)
        rwb[r] = base;
        int wbase = base >> 5;
        wa[r]  = ok ? occ[wbase + wlo] : 0u;
        wb9[r] = ok ? occ[wbase + whi] : 0u;
    }
#pragma unroll
    for (int r = 0; r < 9; ++r) {
        for (int xx = lo; xx <= hi; ++xx) {
            if (r == 4 && xx == x) continue;          // center tap handled by center_k
            unsigned w = ((xx >> 5) == wlo) ? wa[r] : wb9[r];
            if ((w >> (xx & 31)) & 1u) {
                int j = grid[rwb[r] + xx];
                int k = r * 3 + (xx - x + 1);         // 0..26, never 13
                int pos = atomicAdd(&cnt[k], 1);
                if (pos < PAIR_CAP) pairs[k * PAIR_CAP + pos] = make_int2(i, j);
            }
        }
    }
}

__device__ __forceinline__ void accum_row(const float* __restrict__ fr,
                                          const float* __restrict__ wl,
                                          float4 acc[16]) {
#pragma unroll 4
    for (int ci = 0; ci < CIN; ci += 4) {
        float4 f = *(const float4*)(fr + ci);
#pragma unroll
        for (int u = 0; u < 4; ++u) {
            float fv = (&f.x)[u];
            const float4* wr = (const float4*)(wl + (ci + u) * COUT);
#pragma unroll
            for (int c = 0; c < 16; ++c) {
                float4 wv = wr[c];
                acc[c].x += fv * wv.x;
                acc[c].y += fv * wv.y;
                acc[c].z += fv * wv.z;
                acc[c].w += fv * wv.w;
            }
        }
    }
}

__global__ void center_k(const float* __restrict__ feat, const float* __restrict__ w13,
                         float* __restrict__ out, int N) {
    __shared__ float wl[CIN * COUT];
    {
        const float4* ws4 = (const float4*)w13;
        float4* wl4 = (float4*)wl;
        for (int t = threadIdx.x; t < CIN * COUT / 4; t += 256) wl4[t] = ws4[t];
    }
    __syncthreads();
    int i = blockIdx.x * 256 + threadIdx.x;
    if (i >= N) return;
    const float* fr = feat + (size_t)i * CIN;
    float4 acc[16];
#pragma unroll
    for (int c = 0; c < 16; ++c) acc[c] = make_float4(0.f, 0.f, 0.f, 0.f);
    accum_row(fr, wl, acc);
    float4* orow = (float4*)(out + (size_t)i * COUT);
#pragma unroll
    for (int c = 0; c < 16; ++c) orow[c] = acc[c];
}

__global__ void offset_k(const float* __restrict__ feat, const float* __restrict__ weight,
                         const int2* __restrict__ pairs, const int* __restrict__ cnt,
                         float* __restrict__ out) {
    int k = blockIdx.y;
    if (k >= 13) ++k;  // skip center
    int ck = cnt[k];
    if (ck > PAIR_CAP) ck = PAIR_CAP;
    if ((int)blockIdx.x * 256 >= ck) return;  // whole-block early out (uniform, before any sync)
    __shared__ float wl[CIN * COUT];
    {
        const float4* ws4 = (const float4*)(weight + (size_t)k * CIN * COUT);
        float4* wl4 = (float4*)wl;
        for (int t = threadIdx.x; t < CIN * COUT / 4; t += 256) wl4[t] = ws4[t];
    }
    __syncthreads();
    int p = (int)blockIdx.x * 256 + threadIdx.x;
    if (p >= ck) return;
    int2 pr = pairs[k * PAIR_CAP + p];
    const float* fr = feat + (size_t)pr.y * CIN;
    float4 acc[16];
#pragma unroll
    for (int c = 0; c < 16; ++c) acc[c] = make_float4(0.f, 0.f, 0.f, 0.f);
    accum_row(fr, wl, acc);
    float* orow = out + (size_t)pr.x * COUT;
#pragma unroll
    for (int c = 0; c < 16; ++c) {
        atomicAdd(&orow[4 * c + 0], acc[c].x);
        atomicAdd(&orow[4 * c + 1], acc[c].y);
        atomicAdd(&orow[4 * c + 2], acc[c].z);
        atomicAdd(&orow[4 * c + 3], acc[c].w);
    }
}

__global__ void stats_k(const float* __restrict__ out, float* __restrict__ stats, int N) {
    __shared__ float ssum[4][64];
    __shared__ float ssq[4][64];
    int c = threadIdx.x & 63, g = threadIdx.x >> 6;
    float s = 0.f, q = 0.f;
    for (int r = blockIdx.x * 4 + g; r < N; r += gridDim.x * 4) {
        float v = out[(size_t)r * 64 + c];
        s += v;
        q += v * v;
    }
    ssum[g][c] = s;
    ssq[g][c] = q;
    __syncthreads();
    if (threadIdx.x < 64) {
        float ts = ssum[0][c] + ssum[1][c] + ssum[2][c] + ssum[3][c];
        float tq = ssq[0][c] + ssq[1][c] + ssq[2][c] + ssq[3][c];
        atomicAdd(&stats[c], ts);
        atomicAdd(&stats[64 + c], tq);
    }
}

__global__ void norm_k(float* __restrict__ out, const float* __restrict__ stats,
                       const float* __restrict__ gamma, const float* __restrict__ beta, int N) {
    int idx = (int)blockIdx.x * 256 + threadIdx.x;
    int total = N * (COUT / 4);
    if (idx >= total) return;
    int c0 = (idx & 15) * 4;
    float inv = 1.0f / (float)N;
    float4 v = ((const float4*)out)[idx];
    float4 r;
#pragma unroll
    for (int u = 0; u < 4; ++u) {
        int c = c0 + u;
        float mean = stats[c] * inv;
        float var = stats[64 + c] * inv - mean * mean;
        if (var < 0.f) var = 0.f;
        float sc = gamma[c] * rsqrtf(var + EPSV);
        float sh = beta[c] - mean * sc;
        float y = (&v.x)[u] * sc + sh;
        (&r.x)[u] = (y >= 0.f) ? y : SLOPE * y;
    }
    ((float4*)out)[idx] = r;
}

extern "C" void kernel_launch(void* const* d_in, const int* in_sizes, int n_in,
                              void* d_out, int out_size, void* d_ws, size_t ws_size,
                              hipStream_t stream) {
    const float* feat   = (const float*)d_in[0];
    const int*   coords = (const int*)d_in[1];
    const float* weight = (const float*)d_in[2];
    const float* gamma  = (const float*)d_in[3];
    const float* beta   = (const float*)d_in[4];
    float* out = (float*)d_out;
    int N = in_sizes[0] / CIN;

    // workspace layout (total ~44.1 MB)
    char* ws = (char*)d_ws;
    int* grid = (int*)ws;                                   // 39,321,600 B (NOT initialized - gated by occ)
    size_t off = (size_t)GRID_ELEMS * 4;
    int* cnt = (int*)(ws + off);                            // 128 B (27 counters, padded)
    float* stats = (float*)(ws + off + 128);                // 512 B (sum[64], sumsq[64])
    int2* pairs = (int2*)(ws + off + 1024);                 // 27 * PAIR_CAP * 8 B = 3.54 MB
    size_t occ_off = off + 1024 + (size_t)27 * PAIR_CAP * 8;
    unsigned* occ = (unsigned*)(ws + occ_off);              // 1,228,800 B bitmask

    hipMemsetAsync(ws + off, 0, 1024, stream);              // counters + stats
    hipMemsetAsync(occ, 0, (size_t)OCC_WORDS * 4, stream);  // bitmask = 0

    int nb = (N + 255) / 256;
    scatter_k<<<nb, 256, 0, stream>>>(coords, grid, occ, N);
    rulebook_k<<<nb, 256, 0, stream>>>(coords, grid, occ, cnt, pairs, N);
    center_k<<<nb, 256, 0, stream>>>(feat, weight + 13 * CIN * COUT, out, N);
    offset_k<<<dim3(PAIR_CAP / 256, 26), 256, 0, stream>>>(feat, weight, pairs, cnt, out);
    stats_k<<<1024, 256, 0, stream>>>(out, stats, N);
    int nb4 = (N * (COUT / 4) + 255) / 256;
    norm_k<<<nb4, 256, 0, stream>>>(out, stats, gamma, beta, N);
}

// Round 5
// 513.227 us; speedup vs baseline: 1.8738x; 1.8738x over previous
//
#include <hip/hip_runtime.h>

// Sparse submanifold 3x3x3 conv (64->64) + BatchNorm(batch stats) + LeakyReLU(0.01)
// Rulebook strategy, occupancy bitmask, CONTENTION-FREE counters:
//  - rulebook aggregates per-block in LDS, reserves ranges with ONE padded global
//    atomic per (block,k) (27 counters padded 128B apart), bulk-copies pairs.
//  - stats uses padded per-channel counters (128B apart) + fewer blocks.
//   K1 memset cnt/stats (20KB) + occ bitmask (1.2MB)
//   K2 scatter: grid[lin]=i, atomicOr occ bit
//   K3 rulebook (block-aggregated)
//   K4 center GEMM: out = feat @ W[13] (plain store => initializes out)
//   K5 per-offset gather-GEMM, atomicAdd scatter into out (spread lines)
//   K6 channel sum/sumsq reduction (padded atomics)
//   K7 normalize + leaky relu (in place on out)

#define DD 96
#define HH 320
#define WW 320
#define GRID_ELEMS (DD * HH * WW)
#define OCC_WORDS (GRID_ELEMS / 32)   // 1.2 MB; WW%32==0 => rows word-aligned
#define CIN 64
#define COUT 64
#define PAIR_CAP 16384
#define STAGE_CAP 40    // per-(block,k) staging; mean 3.9 hits, P(>40) ~ 0
#define EPSV 1e-5f
#define SLOPE 0.01f

__global__ void scatter_k(const int* __restrict__ coords, int* __restrict__ grid,
                          unsigned* __restrict__ occ, int N) {
    int i = blockIdx.x * 256 + threadIdx.x;
    if (i >= N) return;
    int z = coords[3 * i], y = coords[3 * i + 1], x = coords[3 * i + 2];
    int l = (z * HH + y) * WW + x;
    grid[l] = i;
    atomicOr(&occ[l >> 5], 1u << (l & 31));
}

// Per-voxel probe of L2-resident bitmask; hits staged in LDS; one padded global
// atomic per (block,k) reserves the compact range; bulk copy-out.
__global__ void rulebook_k(const int* __restrict__ coords, const int* __restrict__ grid,
                           const unsigned* __restrict__ occ,
                           int* __restrict__ cnt, int2* __restrict__ pairs, int N) {
    __shared__ int scnt[27];
    __shared__ int sbase[27];
    __shared__ int2 stage[27][STAGE_CAP];
    int tid = threadIdx.x;
    if (tid < 27) scnt[tid] = 0;
    __syncthreads();

    int i = blockIdx.x * 256 + tid;
    if (i < N) {
        int z = coords[3 * i], y = coords[3 * i + 1], x = coords[3 * i + 2];
        int lo = x > 0 ? x - 1 : 0;
        int hi = x < WW - 1 ? x + 1 : WW - 1;
        int wlo = lo >> 5, whi = hi >> 5;

        unsigned wa[9], wb9[9];
        int rwb[9];
#pragma unroll
        for (int r = 0; r < 9; ++r) {
            int zz = z + r / 3 - 1;
            int yy = y + r % 3 - 1;
            bool ok = ((unsigned)zz < DD) && ((unsigned)yy < HH);
            int base = (zz * HH + yy) * WW;      // word-aligned (WW % 32 == 0)
            rwb[r] = base;
            int wbase = base >> 5;
            wa[r]  = ok ? occ[wbase + wlo] : 0u;
            wb9[r] = ok ? occ[wbase + whi] : 0u;
        }
#pragma unroll
        for (int r = 0; r < 9; ++r) {
            for (int xx = lo; xx <= hi; ++xx) {
                if (r == 4 && xx == x) continue;          // center handled by center_k
                unsigned w = ((xx >> 5) == wlo) ? wa[r] : wb9[r];
                if ((w >> (xx & 31)) & 1u) {
                    int j = grid[rwb[r] + xx];
                    int k = r * 3 + (xx - x + 1);         // 0..26, never 13
                    int pos = atomicAdd(&scnt[k], 1);     // LDS atomic: cheap
                    if (pos < STAGE_CAP) stage[k][pos] = make_int2(i, j);
                }
            }
        }
    }
    __syncthreads();
    if (tid < 27) {
        int c = scnt[tid];
        if (c > STAGE_CAP) c = STAGE_CAP;
        scnt[tid] = c;
        if (c > 0) sbase[tid] = atomicAdd(&cnt[tid * 32], c);  // 128B-padded counters
    }
    __syncthreads();
    for (int s = tid; s < 27 * STAGE_CAP; s += 256) {
        int k = s / STAGE_CAP, p = s % STAGE_CAP;
        if (p < scnt[k]) {
            int pos = sbase[k] + p;
            if (pos < PAIR_CAP) pairs[k * PAIR_CAP + pos] = stage[k][p];
        }
    }
}

__device__ __forceinline__ void accum_row(const float* __restrict__ fr,
                                          const float* __restrict__ wl,
                                          float4 acc[16]) {
#pragma unroll 4
    for (int ci = 0; ci < CIN; ci += 4) {
        float4 f = *(const float4*)(fr + ci);
#pragma unroll
        for (int u = 0; u < 4; ++u) {
            float fv = (&f.x)[u];
            const float4* wr = (const float4*)(wl + (ci + u) * COUT);
#pragma unroll
            for (int c = 0; c < 16; ++c) {
                float4 wv = wr[c];
                acc[c].x += fv * wv.x;
                acc[c].y += fv * wv.y;
                acc[c].z += fv * wv.z;
                acc[c].w += fv * wv.w;
            }
        }
    }
}

__global__ void center_k(const float* __restrict__ feat, const float* __restrict__ w13,
                         float* __restrict__ out, int N) {
    __shared__ float wl[CIN * COUT];
    {
        const float4* ws4 = (const float4*)w13;
        float4* wl4 = (float4*)wl;
        for (int t = threadIdx.x; t < CIN * COUT / 4; t += 256) wl4[t] = ws4[t];
    }
    __syncthreads();
    int i = blockIdx.x * 256 + threadIdx.x;
    if (i >= N) return;
    const float* fr = feat + (size_t)i * CIN;
    float4 acc[16];
#pragma unroll
    for (int c = 0; c < 16; ++c) acc[c] = make_float4(0.f, 0.f, 0.f, 0.f);
    accum_row(fr, wl, acc);
    float4* orow = (float4*)(out + (size_t)i * COUT);
#pragma unroll
    for (int c = 0; c < 16; ++c) orow[c] = acc[c];
}

__global__ void offset_k(const float* __restrict__ feat, const float* __restrict__ weight,
                         const int2* __restrict__ pairs, const int* __restrict__ cnt,
                         float* __restrict__ out) {
    int k = blockIdx.y;
    if (k >= 13) ++k;  // skip center
    int ck = cnt[k * 32];
    if (ck > PAIR_CAP) ck = PAIR_CAP;
    if ((int)blockIdx.x * 256 >= ck) return;  // uniform early-out before any sync
    __shared__ float wl[CIN * COUT];
    {
        const float4* ws4 = (const float4*)(weight + (size_t)k * CIN * COUT);
        float4* wl4 = (float4*)wl;
        for (int t = threadIdx.x; t < CIN * COUT / 4; t += 256) wl4[t] = ws4[t];
    }
    __syncthreads();
    int p = (int)blockIdx.x * 256 + threadIdx.x;
    if (p >= ck) return;
    int2 pr = pairs[k * PAIR_CAP + p];
    const float* fr = feat + (size_t)pr.y * CIN;
    float4 acc[16];
#pragma unroll
    for (int c = 0; c < 16; ++c) acc[c] = make_float4(0.f, 0.f, 0.f, 0.f);
    accum_row(fr, wl, acc);
    float* orow = out + (size_t)pr.x * COUT;
#pragma unroll
    for (int c = 0; c < 16; ++c) {
        atomicAdd(&orow[4 * c + 0], acc[c].x);
        atomicAdd(&orow[4 * c + 1], acc[c].y);
        atomicAdd(&orow[4 * c + 2], acc[c].z);
        atomicAdd(&orow[4 * c + 3], acc[c].w);
    }
}

// Padded stats: stats[c*32] = sum_c, stats[(64+c)*32] = sumsq_c (128B per counter)
__global__ void stats_k(const float* __restrict__ out, float* __restrict__ stats, int N) {
    __shared__ float ssum[4][64];
    __shared__ float ssq[4][64];
    int c = threadIdx.x & 63, g = threadIdx.x >> 6;
    float s = 0.f, q = 0.f;
    for (int r = blockIdx.x * 4 + g; r < N; r += gridDim.x * 4) {
        float v = out[(size_t)r * 64 + c];
        s += v;
        q += v * v;
    }
    ssum[g][c] = s;
    ssq[g][c] = q;
    __syncthreads();
    if (threadIdx.x < 64) {
        float ts = ssum[0][c] + ssum[1][c] + ssum[2][c] + ssum[3][c];
        float tq = ssq[0][c] + ssq[1][c] + ssq[2][c] + ssq[3][c];
        atomicAdd(&stats[c * 32], ts);
        atomicAdd(&stats[(64 + c) * 32], tq);
    }
}

__global__ void norm_k(float* __restrict__ out, const float* __restrict__ stats,
                       const float* __restrict__ gamma, const float* __restrict__ beta, int N) {
    int idx = (int)blockIdx.x * 256 + threadIdx.x;
    int total = N * (COUT / 4);
    if (idx >= total) return;
    int c0 = (idx & 15) * 4;
    float inv = 1.0f / (float)N;
    float4 v = ((const float4*)out)[idx];
    float4 r;
#pragma unroll
    for (int u = 0; u < 4; ++u) {
        int c = c0 + u;
        float mean = stats[c * 32] * inv;
        float var = stats[(64 + c) * 32] * inv - mean * mean;
        if (var < 0.f) var = 0.f;
        float sc = gamma[c] * rsqrtf(var + EPSV);
        float sh = beta[c] - mean * sc;
        float y = (&v.x)[u] * sc + sh;
        (&r.x)[u] = (y >= 0.f) ? y : SLOPE * y;
    }
    ((float4*)out)[idx] = r;
}

extern "C" void kernel_launch(void* const* d_in, const int* in_sizes, int n_in,
                              void* d_out, int out_size, void* d_ws, size_t ws_size,
                              hipStream_t stream) {
    const float* feat   = (const float*)d_in[0];
    const int*   coords = (const int*)d_in[1];
    const float* weight = (const float*)d_in[2];
    const float* gamma  = (const float*)d_in[3];
    const float* beta   = (const float*)d_in[4];
    float* out = (float*)d_out;
    int N = in_sizes[0] / CIN;

    // workspace layout (~44.1 MB)
    char* ws = (char*)d_ws;
    int* grid = (int*)ws;                                   // 39.32 MB (gated by occ, no memset)
    size_t off = (size_t)GRID_ELEMS * 4;
    int* cnt = (int*)(ws + off);                            // 27*32 ints padded -> 4KB slot
    float* stats = (float*)(ws + off + 4096);               // 128*32 floats padded = 16KB
    int2* pairs = (int2*)(ws + off + 4096 + 16384);         // 27*PAIR_CAP*8 = 3.54 MB
    size_t occ_off = off + 4096 + 16384 + (size_t)27 * PAIR_CAP * 8;
    unsigned* occ = (unsigned*)(ws + occ_off);              // 1.2 MB bitmask

    hipMemsetAsync(ws + off, 0, 4096 + 16384, stream);      // counters + stats
    hipMemsetAsync(occ, 0, (size_t)OCC_WORDS * 4, stream);  // bitmask = 0

    int nb = (N + 255) / 256;
    scatter_k<<<nb, 256, 0, stream>>>(coords, grid, occ, N);
    rulebook_k<<<nb, 256, 0, stream>>>(coords, grid, occ, cnt, pairs, N);
    center_k<<<nb, 256, 0, stream>>>(feat, weight + 13 * CIN * COUT, out, N);
    offset_k<<<dim3(PAIR_CAP / 256, 26), 256, 0, stream>>>(feat, weight, pairs, cnt, out);
    stats_k<<<256, 256, 0, stream>>>(out, stats, N);
    int nb4 = (N * (COUT / 4) + 255) / 256;
    norm_k<<<nb4, 256, 0, stream>>>(out, stats, gamma, beta, N);
}

// Round 6
// 280.059 us; speedup vs baseline: 3.4340x; 1.8326x over previous
//
#include <hip/hip_runtime.h>

// Sparse submanifold 3x3x3 conv (64->64) + BatchNorm(batch stats) + LeakyReLU(0.01)
// Rulebook strategy, occupancy bitmask, contention-free counters.
//   K1 memset cnt/stats (20KB) + occ bitmask (1.2MB)
//   K2 scatter: grid[lin]=i, atomicOr occ bit
//   K3 rulebook (block-aggregated LDS staging, padded global reservation)
//   K4 center GEMM: out = feat @ W[13] (plain store => initializes out)
//   K5 per-offset gather-GEMM: WAVE-PER-PAIR, lane=channel, coalesced 256B atomic
//   K6 channel sum/sumsq reduction (padded atomics)
//   K7 normalize + leaky relu (in place on out)

#define DD 96
#define HH 320
#define WW 320
#define GRID_ELEMS (DD * HH * WW)
#define OCC_WORDS (GRID_ELEMS / 32)   // 1.2 MB; WW%32==0 => rows word-aligned
#define CIN 64
#define COUT 64
#define PAIR_CAP 16384
#define STAGE_CAP 40    // per-(block,k) staging; mean 3.9 hits, P(>40) ~ 0
#define EPSV 1e-5f
#define SLOPE 0.01f

__global__ void scatter_k(const int* __restrict__ coords, int* __restrict__ grid,
                          unsigned* __restrict__ occ, int N) {
    int i = blockIdx.x * 256 + threadIdx.x;
    if (i >= N) return;
    int z = coords[3 * i], y = coords[3 * i + 1], x = coords[3 * i + 2];
    int l = (z * HH + y) * WW + x;
    grid[l] = i;
    atomicOr(&occ[l >> 5], 1u << (l & 31));
}

// Per-voxel probe of L2-resident bitmask; hits staged in LDS; one padded global
// atomic per (block,k) reserves the compact range; bulk copy-out.
__global__ void rulebook_k(const int* __restrict__ coords, const int* __restrict__ grid,
                           const unsigned* __restrict__ occ,
                           int* __restrict__ cnt, int2* __restrict__ pairs, int N) {
    __shared__ int scnt[27];
    __shared__ int sbase[27];
    __shared__ int2 stage[27][STAGE_CAP];
    int tid = threadIdx.x;
    if (tid < 27) scnt[tid] = 0;
    __syncthreads();

    int i = blockIdx.x * 256 + tid;
    if (i < N) {
        int z = coords[3 * i], y = coords[3 * i + 1], x = coords[3 * i + 2];
        int lo = x > 0 ? x - 1 : 0;
        int hi = x < WW - 1 ? x + 1 : WW - 1;
        int wlo = lo >> 5, whi = hi >> 5;

        unsigned wa[9], wb9[9];
        int rwb[9];
#pragma unroll
        for (int r = 0; r < 9; ++r) {
            int zz = z + r / 3 - 1;
            int yy = y + r % 3 - 1;
            bool ok = ((unsigned)zz < DD) && ((unsigned)yy < HH);
            int base = (zz * HH + yy) * WW;      // word-aligned (WW % 32 == 0)
            rwb[r] = base;
            int wbase = base >> 5;
            wa[r]  = ok ? occ[wbase + wlo] : 0u;
            wb9[r] = ok ? occ[wbase + whi] : 0u;
        }
#pragma unroll
        for (int r = 0; r < 9; ++r) {
            for (int xx = lo; xx <= hi; ++xx) {
                if (r == 4 && xx == x) continue;          // center handled by center_k
                unsigned w = ((xx >> 5) == wlo) ? wa[r] : wb9[r];
                if ((w >> (xx & 31)) & 1u) {
                    int j = grid[rwb[r] + xx];
                    int k = r * 3 + (xx - x + 1);         // 0..26, never 13
                    int pos = atomicAdd(&scnt[k], 1);     // LDS atomic: cheap
                    if (pos < STAGE_CAP) stage[k][pos] = make_int2(i, j);
                }
            }
        }
    }
    __syncthreads();
    if (tid < 27) {
        int c = scnt[tid];
        if (c > STAGE_CAP) c = STAGE_CAP;
        scnt[tid] = c;
        if (c > 0) sbase[tid] = atomicAdd(&cnt[tid * 32], c);  // 128B-padded counters
    }
    __syncthreads();
    for (int s = tid; s < 27 * STAGE_CAP; s += 256) {
        int k = s / STAGE_CAP, p = s % STAGE_CAP;
        if (p < scnt[k]) {
            int pos = sbase[k] + p;
            if (pos < PAIR_CAP) pairs[k * PAIR_CAP + pos] = stage[k][p];
        }
    }
}

__device__ __forceinline__ void accum_row(const float* __restrict__ fr,
                                          const float* __restrict__ wl,
                                          float4 acc[16]) {
#pragma unroll 4
    for (int ci = 0; ci < CIN; ci += 4) {
        float4 f = *(const float4*)(fr + ci);
#pragma unroll
        for (int u = 0; u < 4; ++u) {
            float fv = (&f.x)[u];
            const float4* wr = (const float4*)(wl + (ci + u) * COUT);
#pragma unroll
            for (int c = 0; c < 16; ++c) {
                float4 wv = wr[c];
                acc[c].x += fv * wv.x;
                acc[c].y += fv * wv.y;
                acc[c].z += fv * wv.z;
                acc[c].w += fv * wv.w;
            }
        }
    }
}

__global__ void center_k(const float* __restrict__ feat, const float* __restrict__ w13,
                         float* __restrict__ out, int N) {
    __shared__ float wl[CIN * COUT];
    {
        const float4* ws4 = (const float4*)w13;
        float4* wl4 = (float4*)wl;
        for (int t = threadIdx.x; t < CIN * COUT / 4; t += 256) wl4[t] = ws4[t];
    }
    __syncthreads();
    int i = blockIdx.x * 256 + threadIdx.x;
    if (i >= N) return;
    const float* fr = feat + (size_t)i * CIN;
    float4 acc[16];
#pragma unroll
    for (int c = 0; c < 16; ++c) acc[c] = make_float4(0.f, 0.f, 0.f, 0.f);
    accum_row(fr, wl, acc);
    float4* orow = (float4*)(out + (size_t)i * COUT);
#pragma unroll
    for (int c = 0; c < 16; ++c) orow[c] = acc[c];
}

// Wave-per-pair: lane = output channel. W[k] in LDS row-major (lane stride-1
// read = 2-way bank alias = free); f[j] float4 reads are wave-uniform
// (broadcast); the 64 lanes' atomicAdd is ONE contiguous 256B region (4 lines)
// instead of 64 scattered lines.
__global__ void offset_k(const float* __restrict__ feat, const float* __restrict__ weight,
                         const int2* __restrict__ pairs, const int* __restrict__ cnt,
                         float* __restrict__ out) {
    int k = blockIdx.y;
    if (k >= 13) ++k;  // skip center
    int ck = cnt[k * 32];
    if (ck > PAIR_CAP) ck = PAIR_CAP;
    __shared__ float wl[CIN * COUT];
    {
        const float4* ws4 = (const float4*)(weight + (size_t)k * CIN * COUT);
        float4* wl4 = (float4*)wl;
        for (int t = threadIdx.x; t < CIN * COUT / 4; t += 256) wl4[t] = ws4[t];
    }
    __syncthreads();
    int wave = threadIdx.x >> 6;   // 0..3
    int lane = threadIdx.x & 63;   // output channel
    for (int p = (int)blockIdx.x * 4 + wave; p < ck; p += (int)gridDim.x * 4) {
        int2 pr = pairs[k * PAIR_CAP + p];
        const float4* fr4 = (const float4*)(feat + (size_t)pr.y * CIN);
        float acc = 0.f;
#pragma unroll
        for (int ci4 = 0; ci4 < CIN / 4; ++ci4) {
            float4 f = fr4[ci4];                       // wave-uniform -> broadcast
            acc += f.x * wl[(ci4 * 4 + 0) * COUT + lane];
            acc += f.y * wl[(ci4 * 4 + 1) * COUT + lane];
            acc += f.z * wl[(ci4 * 4 + 2) * COUT + lane];
            acc += f.w * wl[(ci4 * 4 + 3) * COUT + lane];
        }
        atomicAdd(&out[(size_t)pr.x * COUT + lane], acc);  // coalesced 256B region
    }
}

// Padded stats: stats[c*32] = sum_c, stats[(64+c)*32] = sumsq_c (128B per counter)
__global__ void stats_k(const float* __restrict__ out, float* __restrict__ stats, int N) {
    __shared__ float ssum[4][64];
    __shared__ float ssq[4][64];
    int c = threadIdx.x & 63, g = threadIdx.x >> 6;
    float s = 0.f, q = 0.f;
    for (int r = blockIdx.x * 4 + g; r < N; r += gridDim.x * 4) {
        float v = out[(size_t)r * 64 + c];
        s += v;
        q += v * v;
    }
    ssum[g][c] = s;
    ssq[g][c] = q;
    __syncthreads();
    if (threadIdx.x < 64) {
        float ts = ssum[0][c] + ssum[1][c] + ssum[2][c] + ssum[3][c];
        float tq = ssq[0][c] + ssq[1][c] + ssq[2][c] + ssq[3][c];
        atomicAdd(&stats[c * 32], ts);
        atomicAdd(&stats[(64 + c) * 32], tq);
    }
}

__global__ void norm_k(float* __restrict__ out, const float* __restrict__ stats,
                       const float* __restrict__ gamma, const float* __restrict__ beta, int N) {
    int idx = (int)blockIdx.x * 256 + threadIdx.x;
    int total = N * (COUT / 4);
    if (idx >= total) return;
    int c0 = (idx & 15) * 4;
    float inv = 1.0f / (float)N;
    float4 v = ((const float4*)out)[idx];
    float4 r;
#pragma unroll
    for (int u = 0; u < 4; ++u) {
        int c = c0 + u;
        float mean = stats[c * 32] * inv;
        float var = stats[(64 + c) * 32] * inv - mean * mean;
        if (var < 0.f) var = 0.f;
        float sc = gamma[c] * rsqrtf(var + EPSV);
        float sh = beta[c] - mean * sc;
        float y = (&v.x)[u] * sc + sh;
        (&r.x)[u] = (y >= 0.f) ? y : SLOPE * y;
    }
    ((float4*)out)[idx] = r;
}

extern "C" void kernel_launch(void* const* d_in, const int* in_sizes, int n_in,
                              void* d_out, int out_size, void* d_ws, size_t ws_size,
                              hipStream_t stream) {
    const float* feat   = (const float*)d_in[0];
    const int*   coords = (const int*)d_in[1];
    const float* weight = (const float*)d_in[2];
    const float* gamma  = (const float*)d_in[3];
    const float* beta   = (const float*)d_in[4];
    float* out = (float*)d_out;
    int N = in_sizes[0] / CIN;

    // workspace layout (~44.1 MB)
    char* ws = (char*)d_ws;
    int* grid = (int*)ws;                                   // 39.32 MB (gated by occ, no memset)
    size_t off = (size_t)GRID_ELEMS * 4;
    int* cnt = (int*)(ws + off);                            // 27*32 ints padded -> 4KB slot
    float* stats = (float*)(ws + off + 4096);               // 128*32 floats padded = 16KB
    int2* pairs = (int2*)(ws + off + 4096 + 16384);         // 27*PAIR_CAP*8 = 3.54 MB
    size_t occ_off = off + 4096 + 16384 + (size_t)27 * PAIR_CAP * 8;
    unsigned* occ = (unsigned*)(ws + occ_off);              // 1.2 MB bitmask

    hipMemsetAsync(ws + off, 0, 4096 + 16384, stream);      // counters + stats
    hipMemsetAsync(occ, 0, (size_t)OCC_WORDS * 4, stream);  // bitmask = 0

    int nb = (N + 255) / 256;
    scatter_k<<<nb, 256, 0, stream>>>(coords, grid, occ, N);
    rulebook_k<<<nb, 256, 0, stream>>>(coords, grid, occ, cnt, pairs, N);
    center_k<<<nb, 256, 0, stream>>>(feat, weight + 13 * CIN * COUT, out, N);
    offset_k<<<dim3(96, 26), 256, 0, stream>>>(feat, weight, pairs, cnt, out);
    stats_k<<<256, 256, 0, stream>>>(out, stats, N);
    int nb4 = (N * (COUT / 4) + 255) / 256;
    norm_k<<<nb4, 256, 0, stream>>>(out, stats, gamma, beta, N);
}